// Round 7
// baseline (205.632 us; speedup 1.0000x reference)
//
#include <hip/hip_runtime.h>
#include <math.h>

#define NN   10000
#define DEG  16
#define SS   128
#define NRBF 20
#define GG   64
#define RC   10.0f
#define PI_F 3.14159265358979323846f
#define NBK  16          // nodes per fused block
#define PADN 18          // LDS row stride (floats) for [k][node] tiles
#define SARR 88          // per-node reduced-stats stride (floats)

__device__ __forceinline__ float silu_f(float x){
    return x / (1.0f + __expf(-x));
}

// ---------------------------------------------------------------------------
// Kernel 1: phi (uniform across edges at round 0) — fused h + phiW slice.
// 12 blocks; each redundantly computes h, then 32 phiW channels. Zeroes gs.
// ---------------------------------------------------------------------------
__global__ __launch_bounds__(128) void k_phi(
    const float* __restrict__ emb0,
    const float* __restrict__ w1, const float* __restrict__ b1,
    const float* __restrict__ w2, const float* __restrict__ b2,
    float* __restrict__ phiW, float* __restrict__ gs){
    __shared__ float s0[SS];
    __shared__ float hL[SS];
    __shared__ float part[4][32];
    int t = threadIdx.x;
    for (int i = blockIdx.x*128 + t; i < GG*SS; i += 12*128) gs[i] = 0.0f;
    s0[t] = 128.0f * emb0[t];
    __syncthreads();
    float acc = b1[t];
    #pragma unroll 4
    for (int s = 0; s < SS; s++) acc = fmaf(s0[s], w1[s*SS + t], acc);
    hL[t] = silu_f(acc);
    __syncthreads();
    int c  = blockIdx.x*32 + (t & 31);
    int kk = t >> 5;
    float a = 0.0f;
    int sbase = kk * 32;
    #pragma unroll 8
    for (int s = 0; s < 32; s++)
        a = fmaf(hL[sbase + s], w2[(sbase + s)*3*SS + c], a);
    part[kk][t & 31] = a;
    __syncthreads();
    if (t < 32){
        int cc = blockIdx.x*32 + t;
        phiW[cc] = b2[cc] + part[0][t] + part[1][t] + part[2][t] + part[3][t];
    }
}

// ---------------------------------------------------------------------------
// Kernel 2 (FUSED, factorized edge math). 625 blocks x 256 threads,
// NBK=16 nodes/block.
//  E1: thread t owns edge t; computes rbf moments and 16-lane-group
//      shuffle-reduces the 84 per-node stats S2[20], T'[3][20], M, T0[3],
//      invD into sArr.   (state = ph*(fb*M + fw.S2);
//                          sv    = ph*invD*(fb*T0[d] + fw.T'[d]))
//  E2: per-channel dots from sArr -> state/sv written TRANSPOSED to LDS.
//  U:  update phase (U,V matvecs, d, Vnorm, 2-layer MLP) -> atomic gs.
// ---------------------------------------------------------------------------
__global__ __launch_bounds__(256, 4) void k_fused(
    const float* __restrict__ evd, const float* __restrict__ elen,
    const int* __restrict__ ngi,
    const float* __restrict__ filt_w, const float* __restrict__ filt_b,
    const float* __restrict__ phiW,
    const float* __restrict__ u_w, const float* __restrict__ v_w,
    const float* __restrict__ upd_w1, const float* __restrict__ upd_b1,
    const float* __restrict__ upd_w2, const float* __restrict__ upd_b2,
    float* __restrict__ gs){
    __shared__ float sArr[NBK*SARR];     // per-node reduced stats
    __shared__ float svT[SS*PADN];       // sv [k][node]; reused for h
    __shared__ float xT[2*SS*PADN];      // rows 0..127 Vnorm, 128..255 state
    __shared__ float dL[NBK];
    __shared__ int   gIdx[NBK];

    int t  = threadIdx.x;
    int nb = blockIdx.x * NBK;
    if (t < NBK) gIdx[t] = ngi[nb + t];

    // ================= E1: per-edge moments + 16-lane reduction ==========
    {
        int e  = nb*DEG + t;            // global edge; node = t>>4, el = t&15
        int el = t & 15;
        float x = evd[3*e+0], y = evd[3*e+1], z = evd[3*e+2];
        float r = sqrtf(x*x + y*y + z*z);
        float len  = elen[e];
        float mask = (fabsf(len) <= RC) ? 1.0f : 0.0f;
        float cut  = (r < RC) ? 0.5f*(__cosf(PI_F*(1.0f/RC)*r) + 1.0f) : 0.0f;
        float mc   = mask * cut;
        float rs   = fmaxf(r, 1e-12f);
        float inv_rs = 1.0f / rs;
        float base   = (PI_F/RC) * rs;
        float px = mc*x, py = mc*y, pz = mc*z;
        float fr = mask * r * r;

        float* sa = sArr + (t >> 4)*SARR;

        // aux: {M, T0x, T0y, T0z, fr->invD}
        {
            float a0 = mc, a1 = px, a2 = py, a3 = pz, a4 = fr;
            #pragma unroll
            for (int m = 1; m <= 8; m <<= 1){
                a0 += __shfl_xor(a0, m, 16);
                a1 += __shfl_xor(a1, m, 16);
                a2 += __shfl_xor(a2, m, 16);
                a3 += __shfl_xor(a3, m, 16);
                a4 += __shfl_xor(a4, m, 16);
            }
            if (el == 0) sa[80] = a0;
            if (el == 1) sa[81] = a1;
            if (el == 2) sa[82] = a2;
            if (el == 3) sa[83] = a3;
            if (el == 4) sa[84] = (a4 > 0.0f) ? (1.0f/sqrtf(a4)) : 1.0f;
        }

        // 5 chunks x 4 k's: 16 products {mc,px,py,pz} x rb  -> butterfly
        #pragma unroll
        for (int kc = 0; kc < 5; kc++){
            float ql[16];
            #pragma unroll
            for (int kk = 0; kk < 4; kk++){
                int k = kc*4 + kk;
                float rb = __sinf(base * (float)(k+1)) * inv_rs;
                ql[0*4 + kk]  = mc * rb;
                ql[1*4 + kk]  = px * rb;
                ql[2*4 + kk]  = py * rb;
                ql[3*4 + kk]  = pz * rb;
            }
            #pragma unroll
            for (int m = 1; m <= 8; m <<= 1){
                #pragma unroll
                for (int i = 0; i < 16; i++)
                    ql[i] += __shfl_xor(ql[i], m, 16);
            }
            float val = ql[0];
            #pragma unroll
            for (int j = 1; j < 16; j++)
                val = (el == j) ? ql[j] : val;
            // value el: type tau=el>>2 (0:S2,1:Tx,2:Ty,3:Tz), kk=el&3
            sa[(el >> 2)*20 + kc*4 + (el & 3)] = val;
        }
    }
    __syncthreads();

    // ================= E2: per-channel dots ==============================
    {
        int wv = t >> 6, l = t & 63;     // wave wv handles nodes 4wv..4wv+3
        int gcA = SS + l,   gcB = SS + 64 + l;     // m2 -> state
        int gcC = 2*SS + l, gcD = 2*SS + 64 + l;   // m3 -> sv
        float fwA[NRBF], fwB[NRBF], fwC[NRBF], fwD[NRBF];
        #pragma unroll
        for (int k = 0; k < NRBF; k++){
            fwA[k] = filt_w[k*(3*SS) + gcA];
            fwB[k] = filt_w[k*(3*SS) + gcB];
            fwC[k] = filt_w[k*(3*SS) + gcC];
            fwD[k] = filt_w[k*(3*SS) + gcD];
        }
        float fbA = filt_b[gcA], fbB = filt_b[gcB];
        float fbC = filt_b[gcC], fbD = filt_b[gcD];
        float phA = phiW[gcA], phB = phiW[gcB];
        float phC = phiW[gcC], phD = phiW[gcD];
        int s3C = l % 3, s3D = (l + 64) % 3;

        #pragma unroll
        for (int ni = 0; ni < 4; ni++){
            int node = 4*wv + ni;
            const float* sa = sArr + node*SARR;
            float M   = sa[80];
            float t0C = sa[81 + s3C], t0D = sa[81 + s3D];
            float iD  = sa[84];
            float dA = fbA*M,   dB = fbB*M;
            float dC = fbC*t0C, dD = fbD*t0D;
            #pragma unroll
            for (int kc = 0; kc < 5; kc++){
                float4 s2 = *(const float4*)(sa + kc*4);
                float4 tc = *(const float4*)(sa + (1+s3C)*20 + kc*4);
                float4 td = *(const float4*)(sa + (1+s3D)*20 + kc*4);
                int k = kc*4;
                dA = fmaf(s2.x, fwA[k], dA); dA = fmaf(s2.y, fwA[k+1], dA);
                dA = fmaf(s2.z, fwA[k+2], dA); dA = fmaf(s2.w, fwA[k+3], dA);
                dB = fmaf(s2.x, fwB[k], dB); dB = fmaf(s2.y, fwB[k+1], dB);
                dB = fmaf(s2.z, fwB[k+2], dB); dB = fmaf(s2.w, fwB[k+3], dB);
                dC = fmaf(tc.x, fwC[k], dC); dC = fmaf(tc.y, fwC[k+1], dC);
                dC = fmaf(tc.z, fwC[k+2], dC); dC = fmaf(tc.w, fwC[k+3], dC);
                dD = fmaf(td.x, fwD[k], dD); dD = fmaf(td.y, fwD[k+1], dD);
                dD = fmaf(td.z, fwD[k+2], dD); dD = fmaf(td.w, fwD[k+3], dD);
            }
            xT[(SS + l)*PADN + node]      = phA * dA;        // state ch l
            xT[(SS + 64 + l)*PADN + node] = phB * dB;        // state ch 64+l
            svT[l*PADN + node]            = phC * iD * dC;   // sv ch l
            svT[(64 + l)*PADN + node]     = phD * iD * dD;   // sv ch 64+l
        }
    }
    __syncthreads();

    // ================= U: update phase ===================================
    // thread tile: cg = t&31 -> channels c0=4cg..+3 ; ng = t>>5 -> nodes
    // n0 = 2ng, 2 nodes. Weights stream from L1/L2 as coalesced float4.
    int cg = t & 31, ng = t >> 5;
    int c0 = 4*cg, n0 = 2*ng;

    // Phase A: U = sv@u_w, V = sv@v_w
    float accU[4][2], accV[4][2];
    #pragma unroll
    for (int j = 0; j < 4; j++){
        accU[j][0] = accU[j][1] = 0.f;
        accV[j][0] = accV[j][1] = 0.f;
    }
    #pragma unroll 4
    for (int k = 0; k < SS; k++){
        float2 xv = *(const float2*)(svT + k*PADN + n0);
        float4 wu = *(const float4*)(u_w + k*SS + c0);
        float4 wv4 = *(const float4*)(v_w + k*SS + c0);
        float wua[4] = {wu.x, wu.y, wu.z, wu.w};
        float wva[4] = {wv4.x, wv4.y, wv4.z, wv4.w};
        #pragma unroll
        for (int j = 0; j < 4; j++){
            accU[j][0] = fmaf(xv.x, wua[j], accU[j][0]);
            accU[j][1] = fmaf(xv.y, wua[j], accU[j][1]);
            accV[j][0] = fmaf(xv.x, wva[j], accV[j][0]);
            accV[j][1] = fmaf(xv.y, wva[j], accV[j][1]);
        }
    }
    // d[n] = sum_c U*V (reduce across the 32 channel-groups in each half)
    float pd0 = 0.f, pd1 = 0.f;
    #pragma unroll
    for (int j = 0; j < 4; j++){
        pd0 = fmaf(accU[j][0], accV[j][0], pd0);
        pd1 = fmaf(accU[j][1], accV[j][1], pd1);
    }
    #pragma unroll
    for (int m = 1; m <= 16; m <<= 1){
        pd0 += __shfl_xor(pd0, m);
        pd1 += __shfl_xor(pd1, m);
    }
    if (cg == 0){ dL[n0] = pd0; dL[n0+1] = pd1; }
    // Vnorm = sqrt(3)*|V| into xT rows 0..127
    const float SQ3 = 1.7320508075688772f;
    #pragma unroll
    for (int j = 0; j < 4; j++){
        xT[(c0+j)*PADN + n0]     = SQ3 * fabsf(accV[j][0]);
        xT[(c0+j)*PADN + n0 + 1] = SQ3 * fabsf(accV[j][1]);
    }
    __syncthreads();
    float d30 = 3.0f*dL[n0], d31 = 3.0f*dL[n0+1];

    // Phase B: h = silu([Vnorm,state] @ upd_w1 + b1)  -> svT reused as h
    float accH[4][2];
    #pragma unroll
    for (int j = 0; j < 4; j++) accH[j][0] = accH[j][1] = 0.f;
    #pragma unroll 4
    for (int k = 0; k < 2*SS; k++){
        float2 xv = *(const float2*)(xT + k*PADN + n0);
        float4 w4 = *(const float4*)(upd_w1 + k*SS + c0);
        float wa[4] = {w4.x, w4.y, w4.z, w4.w};
        #pragma unroll
        for (int j = 0; j < 4; j++){
            accH[j][0] = fmaf(xv.x, wa[j], accH[j][0]);
            accH[j][1] = fmaf(xv.y, wa[j], accH[j][1]);
        }
    }
    {
        float4 b1v = *(const float4*)(upd_b1 + c0);
        float ba[4] = {b1v.x, b1v.y, b1v.z, b1v.w};
        #pragma unroll
        for (int j = 0; j < 4; j++){
            svT[(c0+j)*PADN + n0]     = silu_f(accH[j][0] + ba[j]);
            svT[(c0+j)*PADN + n0 + 1] = silu_f(accH[j][1] + ba[j]);
        }
    }
    __syncthreads();

    // Phase C: a_sv (w2 cols S..2S), a_ss (cols 2S..3S)
    float a2[4][2], a3[4][2];
    #pragma unroll
    for (int j = 0; j < 4; j++){
        a2[j][0] = a2[j][1] = 0.f;
        a3[j][0] = a3[j][1] = 0.f;
    }
    #pragma unroll 4
    for (int k = 0; k < SS; k++){
        float2 hx = *(const float2*)(svT + k*PADN + n0);
        float4 w2 = *(const float4*)(upd_w2 + k*3*SS + SS   + c0);
        float4 w3 = *(const float4*)(upd_w2 + k*3*SS + 2*SS + c0);
        float w2a[4] = {w2.x, w2.y, w2.z, w2.w};
        float w3a[4] = {w3.x, w3.y, w3.z, w3.w};
        #pragma unroll
        for (int j = 0; j < 4; j++){
            a2[j][0] = fmaf(hx.x, w2a[j], a2[j][0]);
            a2[j][1] = fmaf(hx.y, w2a[j], a2[j][1]);
            a3[j][0] = fmaf(hx.x, w3a[j], a3[j][0]);
            a3[j][1] = fmaf(hx.y, w3a[j], a3[j][1]);
        }
    }
    float4 bsv4 = *(const float4*)(upd_b2 + SS   + c0);
    float4 bss4 = *(const float4*)(upd_b2 + 2*SS + c0);
    float bsv[4] = {bsv4.x, bsv4.y, bsv4.z, bsv4.w};
    float bss[4] = {bss4.x, bss4.y, bss4.z, bss4.w};
    int g0 = gIdx[n0], g1 = gIdx[n0+1];
    #pragma unroll
    for (int j = 0; j < 4; j++){
        float ns0 = (a3[j][0] + bss[j]) + d30*(a2[j][0] + bsv[j]);
        float ns1 = (a3[j][1] + bss[j]) + d31*(a2[j][1] + bsv[j]);
        atomicAdd(&gs[g0*SS + c0 + j], ns0);
        atomicAdd(&gs[g1*SS + c0 + j], ns1);
    }
}

// ---------------------------------------------------------------------------
// Kernel 3: readout per graph
// ---------------------------------------------------------------------------
__global__ __launch_bounds__(128) void k_out(
    const float* __restrict__ gs,
    const float* __restrict__ w1, const float* __restrict__ b1,
    const float* __restrict__ w2, const float* __restrict__ b2,
    float* __restrict__ out){
    __shared__ float gsL[SS];
    __shared__ float red[2];
    int g = blockIdx.x, t = threadIdx.x;
    gsL[t] = gs[g*SS + t];
    __syncthreads();
    float acc = b1[t];
    #pragma unroll 4
    for (int s = 0; s < SS; s++) acc = fmaf(gsL[s], w1[s*SS + t], acc);
    float p = silu_f(acc) * w2[t];
    for (int off = 32; off; off >>= 1) p += __shfl_down(p, off);
    if ((t & 63) == 0) red[t >> 6] = p;
    __syncthreads();
    if (t == 0) out[g] = red[0] + red[1] + b2[0];
}

extern "C" void kernel_launch(void* const* d_in, const int* in_sizes, int n_in,
                              void* d_out, int out_size, void* d_ws, size_t ws_size,
                              hipStream_t stream) {
    const float* evd     = (const float*)d_in[0];
    const float* elen    = (const float*)d_in[1];
    const int*   ngi     = (const int*)  d_in[3];
    const float* emb0    = (const float*)d_in[5];
    const float* phi_w1  = (const float*)d_in[6];
    const float* phi_b1  = (const float*)d_in[7];
    const float* phi_w2  = (const float*)d_in[8];
    const float* phi_b2  = (const float*)d_in[9];
    const float* filt_w  = (const float*)d_in[10];
    const float* filt_b  = (const float*)d_in[11];
    const float* u_w     = (const float*)d_in[12];
    const float* v_w     = (const float*)d_in[13];
    const float* upd_w1  = (const float*)d_in[14];
    const float* upd_b1  = (const float*)d_in[15];
    const float* upd_w2  = (const float*)d_in[16];
    const float* upd_b2  = (const float*)d_in[17];
    const float* out_w1  = (const float*)d_in[18];
    const float* out_b1  = (const float*)d_in[19];
    const float* out_w2  = (const float*)d_in[20];
    const float* out_b2  = (const float*)d_in[21];

    float* ws   = (float*)d_ws;
    float* phiW = ws;            // 384 (pad to 512)
    float* gs   = ws + 512;      // G*S

    k_phi<<<12, 128, 0, stream>>>(emb0, phi_w1, phi_b1, phi_w2, phi_b2, phiW, gs);
    k_fused<<<NN/NBK, 256, 0, stream>>>(evd, elen, ngi, filt_w, filt_b, phiW,
                                        u_w, v_w, upd_w1, upd_b1, upd_w2, upd_b2, gs);
    k_out<<<GG, 128, 0, stream>>>(gs, out_w1, out_b1, out_w2, out_b2, (float*)d_out);
}